// Round 12
// baseline (149.799 us; speedup 1.0000x reference)
//
#include <hip/hip_runtime.h>
#include <stdint.h>
#include <stddef.h>

// ---------------- problem constants ----------------
// B=2048, F0=39, D=16, layers 128/128/128, xk halves to 64 after each layer.
// R23: u-GEMM. z[b,s,d] = sum_{h,k} W[h,k,s] * u[b,h,k,d], u = bf16(x0*xk).
// R22 counters: matrix-busy 25.7us == the 25us MFMA floor (62.7GF/2.5PF) but
// wall 73.5us: the per-h combine (MFMA -> AGPR readback -> z+=xs*y -> reuse)
// is both the VALU load (~26 instr/wave-step) and the all-wave stall window.
// Fix: fold xs into the MFMA K-axis. Unlike R14-R17's per-wave G build (died
// in regalloc), u is s-INVARIANT -> built ONCE per block in LDS (1024 thr x
// 8 vals, ~20 VALU/thread/step), consumed by all 16 waves via ds_read_b128.
// h-loop: build u(h+1) into buf^1 || consume buf (8 b128 + 8 MFMA -> persistent
// acc) || 1 barrier. No VALU combine, no y round-trip, no Bf reg cache.
// Layouts lane-linear (conflict-free): u/XKT as [b][k/8][d][8] (build rw at
// tid*16B; consume = natural b128 pattern); xs keeps odd-45 stride.
// LDS 72192B (X0T 23040 f32 + XKT 16384 bf16 + 2x u 16384) -> dynamic.
// Numerics: ONE extra bf16 rounding/term vs champion (R15-R17 precedent:
// absmax 0.25, passed). Falsifiers: WRITE_SIZE must stay 2048KB, no slow
// dispatch-0; else revert to R22 (73.5us main).
#define F0N  39
#define SN   128
#define NB   8             // batches per block
#define X0TS 45            // f32 stride of X0T row (b,d): odd => conflict-free xs reads
#define WBLK 8192          // u16 per (L,h) W block: 8 s-tiles x 2 chunks x 512
#define NHB2 234           // 3*39*2 prepass blocks (one per (L,h,k-half))
// dynamic LDS carve (bytes, all 16B-aligned)
#define X0T_BYTES 23040    // 8*16*45*4
#define XKT_OFF   23040
#define U0_OFF    39424    // XKT_OFF + 8*8*16*8*2
#define U1_OFF    55808
#define SMEM_TOTAL 72192

typedef __attribute__((ext_vector_type(8))) short short8;   // MFMA A/B operand
typedef __attribute__((ext_vector_type(4))) float floatx4;  // MFMA accumulator
typedef __attribute__((ext_vector_type(8))) float floatx8;
typedef __attribute__((ext_vector_type(8))) __bf16 bf16x8;

__device__ __forceinline__ uint16_t f2bf(float f) {         // RNE f32->bf16
  uint32_t u = __float_as_uint(f);
  u += 0x7fffu + ((u >> 16) & 1u);
  return (uint16_t)(u >> 16);
}

// build 8 u values: u[b][k8][d][j] = bf16(xs * xk[j]); all addrs tid-linear
__device__ __forceinline__ void build_u(const float* X0T, const uint16_t* XKT,
                                        uint16_t* dst, int xrow, int toff, int hn) {
  float xs = X0T[xrow + hn];                    // x0[b][hn][d] (col 39 = 0 pad)
  short8 xkv = *(const short8*)(XKT + toff);    // xk[b][k8*8..+7][d]
  bf16x8 xb = __builtin_bit_cast(bf16x8, xkv);
  floatx8 xf = __builtin_convertvector(xb, floatx8);
  floatx8 pf;
#pragma unroll
  for (int j = 0; j < 8; ++j) pf[j] = xf[j] * xs;
  *(short8*)(dst + toff) =
      __builtin_bit_cast(short8, __builtin_convertvector(pf, bf16x8));
}

// ---------------- pre-pass: W fp32 -> bf16 A-fragment blocks ----------------
// One block per (L,h,ch). Output layout identical to R6-R22 (verified):
//   wt[(L*39+h)*WBLK + (st*2+ch)*512 + lane*8 + j],
//   value = W[h][k=ch*32+quad*8+j][s=st*16+l16].
__global__ __launch_bounds__(256) void cin_prepass(
    const float* __restrict__ w0, const float* __restrict__ w1,
    const float* __restrict__ w2, uint16_t* __restrict__ wt) {
  __shared__ float T[32 * 132];               // [k_local][s], +4 pad floats/row
  const int bc = blockIdx.x;                  // 0..233
  const int ch = bc & 1;
  const int lh = bc >> 1;                     // 0..116
  const int L = lh / F0N;
  const int h = lh - L * F0N;
  const float* W = (L == 0) ? w0 : ((L == 1) ? w1 : w2);
  const int fk = (L == 0) ? 39 : 64;
  const int tid = threadIdx.x;

  for (int e = tid; e < 4096; e += 256) {     // coalesced fp32 read
    int kc = e >> 7, s = e & 127;
    int k = ch * 32 + kc;
    T[kc * 132 + s] = (k < fk) ? W[(h * fk + k) * SN + s] : 0.0f;
  }
  __syncthreads();
  uint32_t* dst = (uint32_t*)(wt + (size_t)lh * WBLK);
  for (int i = tid; i < 2048; i += 256) {     // coalesced u32 writes, frag order
    int st = i >> 8, w = i & 255;
    int ln = w >> 2, jp = w & 3;
    int quad = ln >> 4, l16 = ln & 15;
    int k0 = quad * 8 + jp * 2;               // local k within this half
    int s = st * 16 + l16;
    dst[(size_t)(st * 2 + ch) * 256 + w] =
        (uint32_t)f2bf(T[k0 * 132 + s]) | ((uint32_t)f2bf(T[(k0 + 1) * 132 + s]) << 16);
  }
}

// ---------------- fused main kernel ----------------
// 256 blocks x 1024 threads (16 waves), 1 block/CU, 4 waves/SIMD.
// Wave (st,bg): s-tile st x batches bg*4..+3. Per layer: build u(0); barrier;
// h-loop {dist-1 W prefetch; build u(h+1) -> buf^1; per bi: 2 ds_read_b128
// u-frags + 2 MFMA into persistent z[bi]; swap; barrier}; epilogue.
// Build thread map: bb=tid>>7, k8=(tid>>4)&7, dd=tid&15 -> u16 off = tid*8
// (lane-linear, conflict-free). Consume: u off = bg*4096 + bi*1024 + c*512 +
// quad*128 + l16*8 (natural b128 pattern, conflict-free).
__global__ __launch_bounds__(1024) void cin_main(
    const float* __restrict__ x,       // (2048, 39, 16) fp32
    const float* __restrict__ bias0, const float* __restrict__ bias1,
    const float* __restrict__ bias2,
    const uint16_t* __restrict__ wt,   // A-frag bf16 weights (d_ws)
    float* __restrict__ out) {         // (2048, 256) fp32

  extern __shared__ __align__(16) char smem[];
  float*    X0T = (float*)smem;                       // x0[b][d][h] f32
  uint16_t* XKT = (uint16_t*)(smem + XKT_OFF);        // xk[b][k/8][d][8] bf16
  uint16_t* U0  = (uint16_t*)(smem + U0_OFF);         // u   [b][k/8][d][8] bf16
  uint16_t* U1  = (uint16_t*)(smem + U1_OFF);

  const int tid  = threadIdx.x;
  const int lane = tid & 63;
  const int wave = tid >> 6;           // 0..15
  const int st   = wave >> 1;          // s-tile 0..7
  const int bg   = wave & 1;           // batch group 0..1
  const int l16  = lane & 15;          // = d (output col)
  const int quad = lane >> 4;
  const int bbase = blockIdx.x * NB;

  // build-role indices (all LDS traffic tid-linear)
  const int xrow = ((tid >> 7) * 16 + (tid & 15)) * X0TS;  // (bb*16+dd)*45
  const int toff = tid * 8;                                // u16 units

  // zero X0T (h-pad cols 39..44 must read 0)
  {
#pragma unroll
    for (int i = 0; i < 6; i++) { int e = tid + 1024 * i; if (e < NB * 16 * X0TS) X0T[e] = 0.f; }
  }
  __syncthreads();

  // fill X0T[b][d][h] = x[bbase+b][h][d]  (coalesced read, LDS transpose-scatter)
#pragma unroll
  for (int it = 0; it < 5; ++it) {
    int e = tid + it * 1024;           // e = (b*39 + h)*16 + d, total 4992
    if (e < NB * F0N * 16) {
      float v = x[(size_t)bbase * (F0N * 16) + e];
      int d = e & 15, p = e >> 4;
      int b = p / F0N, h = p - b * F0N;
      X0T[(b * 16 + d) * X0TS + h] = v;
    }
  }
  __syncthreads();

  // layer-0 XKT: xk = x0 transposed, k-pad zeros; thread (bb,k8,dd) writes 8
  {
    int k8 = (tid >> 4) & 7;
    uint16_t vals[8];
#pragma unroll
    for (int j = 0; j < 8; ++j) {
      int k = k8 * 8 + j;
      vals[j] = (k < F0N) ? f2bf(X0T[xrow + k]) : (uint16_t)0;
    }
    *(short8*)(XKT + toff) = *(short8*)vals;
  }
  __syncthreads();   // XKT visible for u builds

  // per-lane constant W offset (u16 units) — bg-pair waves share lines (L1)
  const int stlane = st * 1024 + lane * 8;
  // per-wave u consume base (u16 units)
  const int ulane = bg * 4096 + quad * 128 + l16 * 8;

  // seed dist-1 W prefetch: ih = 0 (L0, h0)
  short8 Wc0 = *(const short8*)(wt + stlane);
  short8 Wc1 = *(const short8*)(wt + stlane + 512);

  int ih = 0;                          // flat weight-block index = L*39 + h
#pragma unroll 1
  for (int L = 0; L < 3; ++L) {
    uint16_t* ua  = U0;                // consume buffer (holds u(h))
    uint16_t* ubn = U1;                // build target   (u(h+1))

    build_u(X0T, XKT, ua, xrow, toff, 0);   // u(0)
    __syncthreads();

    floatx4 z[4] = {};                 // persistent accumulators (MFMA C)

#pragma unroll 1
    for (int h = 0; h < 39; ++h, ++ih) {
      // dist-1 W prefetch; uniform SALU base (ih+1 at h=38 IS next layer's h0)
      int ihn = ih + 1;
      if (ihn > 116) ihn = 116;
      const uint16_t* wb = wt + (size_t)ihn * WBLK + stlane;
      short8 Wn0 = *(const short8*)(wb);
      short8 Wn1 = *(const short8*)(wb + 512);

      // build u(h+1) into the other buffer (h=38 -> hn=39 reads zero pad;
      // harmless, overwritten by next layer's u(0))
      build_u(X0T, XKT, ubn, xrow, toff, h + 1);

      // consume u(h): per bi 2 x ds_read_b128 + 2 MFMA into persistent acc
#pragma unroll
      for (int bi = 0; bi < 4; ++bi) {
        const uint16_t* ur = ua + ulane + bi * 1024;
        short8 u0 = *(const short8*)(ur);          // k chunk 0 (k 0..31)
        short8 u1 = *(const short8*)(ur + 512);    // k chunk 1 (k 32..63)
        z[bi] = __builtin_amdgcn_mfma_f32_16x16x32_bf16(Wc0, u0, z[bi], 0, 0, 0);
        z[bi] = __builtin_amdgcn_mfma_f32_16x16x32_bf16(Wc1, u1, z[bi], 0, 0, 0);
      }
      Wc0 = Wn0;
      Wc1 = Wn1;
      { uint16_t* t = ua; ua = ubn; ubn = t; }
      __syncthreads();   // u(h+1) visible; consume reads of ua done
    }

    // ---- epilogue: bias+relu; xk handoff (new layout); sum_d -> out ----
    const float* bp = (L == 0) ? bias0 : ((L == 1) ? bias1 : bias2);
#pragma unroll
    for (int bi = 0; bi < 4; ++bi) {
      const int b = bg * 4 + bi;
#pragma unroll
      for (int r = 0; r < 4; ++r) {
        float t = fmaxf(z[bi][r] + bp[st * 16 + quad * 4 + r], 0.f);
        if (L < 2 && st < 4) {             // xk = relu(z)[:, :64]; k = s < 64
          int s = st * 16 + quad * 4 + r;
          XKT[((b * 8 + (s >> 3)) * 16 + l16) * 8 + (s & 7)] = f2bf(t);
        }
        float s4 = t;                       // reduce over d = l16 (bits 0..3)
        s4 += __shfl_xor(s4, 1);
        s4 += __shfl_xor(s4, 2);
        s4 += __shfl_xor(s4, 4);
        s4 += __shfl_xor(s4, 8);
        if (l16 == 0) {
          int s = st * 16 + quad * 4 + r;
          // concat: L0 s64:128 -> 0:64 ; L1 s64:128 -> 64:128 ; L2 s -> 128:256
          if (L == 2)       out[(size_t)(bbase + b) * 256 + 128 + s] = s4;
          else if (s >= 64) out[(size_t)(bbase + b) * 256 + L * 64 + (s - 64)] = s4;
        }
      }
    }
    if (L < 2) __syncthreads();   // handoff visible before next layer's u(0) build
  }
}

extern "C" void kernel_launch(void* const* d_in, const int* in_sizes, int n_in,
                              void* d_out, int out_size, void* d_ws, size_t ws_size,
                              hipStream_t stream) {
  (void)in_sizes; (void)n_in; (void)out_size; (void)ws_size;
  const float* x  = (const float*)d_in[0];
  const float* w0 = (const float*)d_in[1];
  const float* b0 = (const float*)d_in[2];
  const float* w1 = (const float*)d_in[3];
  const float* b1 = (const float*)d_in[4];
  const float* w2 = (const float*)d_in[5];
  const float* b2 = (const float*)d_in[6];
  uint16_t* wt    = (uint16_t*)d_ws;   // 117 * 8192 * 2 = 1,916,928 B

  static bool smem_cfg = false;        // host-side, graph-capture-safe
  if (!smem_cfg) {
    (void)hipFuncSetAttribute((const void*)cin_main,
                              hipFuncAttributeMaxDynamicSharedMemorySize,
                              SMEM_TOTAL);
    smem_cfg = true;
  }

  cin_prepass<<<NHB2, 256, 0, stream>>>(w0, w1, w2, wt);
  cin_main<<<256, 1024, SMEM_TOTAL, stream>>>(x, b0, b1, b2, wt, (float*)d_out);
}